// Round 8
// baseline (765.187 us; speedup 1.0000x reference)
//
#include <hip/hip_runtime.h>
#include <hip/hip_bf16.h>

typedef unsigned short ushort_t;
typedef __attribute__((ext_vector_type(8))) short short8;
typedef __attribute__((ext_vector_type(4))) float f32x4;
typedef __attribute__((ext_vector_type(4))) unsigned int uint4v;

#define NQ      2048
#define ND      512
#define NDB     100000
#define TOPK    10
#define NCHUNK  98
#define CHUNK_N 1024                  // 8 tiles * 128
#define NPAD    (NCHUNK * CHUNK_N)    // 100352 >= 100000
#define QTILES  (NQ / 256)            // 8
#define NTILES  (CHUNK_N / 128)       // 8
#define NWG     (NCHUNK * QTILES)     // 784 = 8 * 98
#define PERXCD  (NWG / 8)             // 98

// async global->LDS, 16B per lane, wave-uniform LDS base + lane*16
#define GL2LDS(gp, lp) __builtin_amdgcn_global_load_lds(                      \
    (const __attribute__((address_space(1))) void*)(gp),                     \
    (__attribute__((address_space(3))) void*)(lp), 16, 0, 0)

// ---------- fp32 -> bf16 (round to nearest even) ----------
static __device__ inline ushort_t f2bf(float x) {
    unsigned u = __float_as_uint(x);
    unsigned r = (u + 0x7FFFu + ((u >> 16) & 1u)) >> 16;
    return (ushort_t)r;
}

// ---------- row L2-normalize, fp32 -> bf16, one wave per row; zero-fill pad rows ----------
__global__ void normalize_rows(const float* __restrict__ in, ushort_t* __restrict__ out,
                               int nvalid, int ntotal) {
    int row  = blockIdx.x * 4 + (threadIdx.x >> 6);
    int lane = threadIdx.x & 63;
    if (row >= ntotal) return;
    uint4v pk;
    if (row >= nvalid) {
        pk[0] = 0u; pk[1] = 0u; pk[2] = 0u; pk[3] = 0u;
    } else {
        const float4* src = reinterpret_cast<const float4*>(in + (size_t)row * ND);
        float4 v0 = src[lane * 2];
        float4 v1 = src[lane * 2 + 1];
        float s = v0.x*v0.x + v0.y*v0.y + v0.z*v0.z + v0.w*v0.w
                + v1.x*v1.x + v1.y*v1.y + v1.z*v1.z + v1.w*v1.w;
        #pragma unroll
        for (int off = 32; off; off >>= 1) s += __shfl_xor(s, off, 64);
        float r = rsqrtf(s);
        pk[0] = (unsigned)f2bf(v0.x * r) | ((unsigned)f2bf(v0.y * r) << 16);
        pk[1] = (unsigned)f2bf(v0.z * r) | ((unsigned)f2bf(v0.w * r) << 16);
        pk[2] = (unsigned)f2bf(v1.x * r) | ((unsigned)f2bf(v1.y * r) << 16);
        pk[3] = (unsigned)f2bf(v1.z * r) | ((unsigned)f2bf(v1.w * r) << 16);
    }
    *reinterpret_cast<uint4v*>(out + (size_t)row * ND + lane * 8) = pk;
}

__device__ inline void topk_insert(float (&top)[TOPK], float x) {
    #pragma unroll
    for (int i = 0; i < TOPK; ++i) {
        float mx = fmaxf(top[i], x);
        x = fminf(top[i], x);
        top[i] = mx;
    }
}

// ---------- fused GEMM + per-chunk top-10 ----------
// 512 threads, 8 waves (2 per SIMD in-block -> ds_read/VALU hides under SIMD-mate MFMA).
// Wave wv owns queries [wv*32, wv*32+32) of the 256-q block tile, x 128 n per n-tile.
// A K-panel in registers (loaded once). B triple-buffered in LDS, depth-2 prefetch,
// ONE raw s_barrier + counted vmcnt(2) per K-step (never a full drain in steady state).
// SWAPPED mfma(B,A), 16x16x32 with R6's proven conflict-free swizzled reads:
// acc[qs][ns][r] = score[n][q = qs*16+(lane&15)] -> top-10 entirely in registers.
__global__ __launch_bounds__(512, 2)
void knn_chunk(const ushort_t* __restrict__ qb, const ushort_t* __restrict__ dbb,
               float* __restrict__ partial) {
    // XCD-chunked swizzle: co-locate blocks sharing B-chunks on one XCD
    const int logical = (blockIdx.x % 8) * PERXCD + blockIdx.x / 8;
    const int qt = logical & (QTILES - 1);
    const int nc = logical >> 3;       // QTILES == 8
    const int t = threadIdx.x, lane = t & 63, wv = t >> 6;   // wv in 0..7

    __shared__ __align__(16) ushort_t Bs[3][128 * 64];   // 48 KB

    // ---- A K-panel in registers: af[qs][kk] (B-operand layout of mfma_16x16x32):
    // q = qs*16 + (lane&15), k = kk*32 + (lane>>4)*8 + j
    short8 af[2][16];
    {
        const ushort_t* aseg = qb + (size_t)(qt * 256 + wv * 32) * ND;
        #pragma unroll
        for (int qs = 0; qs < 2; ++qs) {
            const ushort_t* ap = aseg + (size_t)(qs * 16 + (lane & 15)) * ND + (lane >> 4) * 8;
            #pragma unroll
            for (int kk = 0; kk < 16; ++kk)
                af[qs][kk] = *reinterpret_cast<const short8*>(ap + kk * 32);
        }
    }

    float top[2][TOPK];
    #pragma unroll
    for (int qs = 0; qs < 2; ++qs)
        #pragma unroll
        for (int i = 0; i < TOPK; ++i) top[qs][i] = -1e30f;

    const size_t nchunkbase = (size_t)nc * CHUNK_N;
    const int cb = wv * 128;          // wave's 16B-chunk base among the tile's 1024 chunks

    // stage one 128x64 B K-slice into dst (each wave stages 2 of 16 gl2lds);
    // inverse-swizzled global source + linear LDS dest (gload_lds requirement)
    auto stageB = [&](size_t rowbase, int kbase, ushort_t* dst) {
        const ushort_t* bseg = dbb + rowbase * ND;
        #pragma unroll
        for (int i = 0; i < 2; ++i) {
            const int cid = cb + i * 64 + lane;
            const int row = cid >> 3;
            const int c   = (cid & 7) ^ (row & 7);
            GL2LDS(bseg + (size_t)row * ND + kbase + c * 8, dst + (cb + i * 64) * 8);
        }
    };

    ushort_t* r0 = &Bs[0][0];
    ushort_t* r1 = &Bs[1][0];
    ushort_t* r2 = &Bs[2][0];

    // prologue: stage steps 0 and 1 (depth 2)
    stageB(nchunkbase, 0, r0);
    stageB(nchunkbase, 64, r1);

    #pragma unroll 1
    for (int nt = 0; nt < NTILES; ++nt) {
        f32x4 acc[2][8];
        #pragma unroll
        for (int a = 0; a < 2; ++a)
            #pragma unroll
            for (int b = 0; b < 8; ++b)
                acc[a][b] = (f32x4){0.f, 0.f, 0.f, 0.f};

        #pragma unroll
        for (int ks = 0; ks < 8; ++ks) {
            // counted wait: own share of current buffer landed; next buffer's 2 stay in flight
            if (ks == 7 && nt == NTILES - 1) {
                asm volatile("s_waitcnt vmcnt(0)" ::: "memory");
            } else {
                asm volatile("s_waitcnt vmcnt(2)" ::: "memory");
            }
            __builtin_amdgcn_s_barrier();
            asm volatile("" ::: "memory");      // no LDS reads hoist above the barrier

            ushort_t* tgt = ((ks + 2) % 3 == 0) ? r0 : ((ks + 2) % 3 == 1) ? r1 : r2;
            const ushort_t* cur = (ks % 3 == 0) ? r0 : (ks % 3 == 1) ? r1 : r2;

            // issue depth-2 stage first (buffer was last read at step ks-1; safe after barrier)
            if (ks <= 5)                stageB(nchunkbase + nt * 128, (ks + 2) * 64, tgt);
            else if (nt + 1 < NTILES)   stageB(nchunkbase + (nt + 1) * 128, (ks - 6) * 64, tgt);

            #pragma unroll
            for (int ksub = 0; ksub < 2; ++ksub) {
                const int j0 = (ksub * 4 + (lane >> 4)) ^ (lane & 7);   // swizzled 16B-chunk in row
                short8 bf[8];
                #pragma unroll
                for (int ns = 0; ns < 8; ++ns)
                    bf[ns] = *reinterpret_cast<const short8*>(cur + (ns * 16 + (lane & 15)) * 64 + j0 * 8);
                __builtin_amdgcn_s_setprio(1);
                #pragma unroll
                for (int qs = 0; qs < 2; ++qs)
                    #pragma unroll
                    for (int ns = 0; ns < 8; ++ns)
                        acc[qs][ns] = __builtin_amdgcn_mfma_f32_16x16x32_bf16(bf[ns], af[qs][ks * 2 + ksub], acc[qs][ns], 0, 0, 0);
                __builtin_amdgcn_s_setprio(0);
            }
        }
        // rotate buffers: 8 steps == 2 (mod 3)
        { ushort_t* n0 = r2; ushort_t* n1 = r0; ushort_t* n2 = r1; r0 = n0; r1 = n1; r2 = n2; }

        // in-register selection; prefetched stages keep flying underneath
        #pragma unroll
        for (int qs = 0; qs < 2; ++qs) {
            float m = -1e30f;
            #pragma unroll
            for (int ns = 0; ns < 8; ++ns) {
                float m0 = fmaxf(fmaxf(acc[qs][ns][0], acc[qs][ns][1]),
                                 fmaxf(acc[qs][ns][2], acc[qs][ns][3]));
                m = fmaxf(m, m0);
            }
            if (m > top[qs][TOPK - 1]) {
                #pragma unroll
                for (int ns = 0; ns < 8; ++ns)
                    #pragma unroll
                    for (int r = 0; r < 4; ++r) {
                        float v = acc[qs][ns][r];
                        if (v > top[qs][TOPK - 1]) topk_insert(top[qs], v);
                    }
            }
        }
    }

    // butterfly merge across the 4 lanes sharing each query (lane ^ 16, lane ^ 32)
    #pragma unroll
    for (int qs = 0; qs < 2; ++qs) {
        #pragma unroll
        for (int step = 16; step <= 32; step <<= 1) {
            float other[TOPK];
            #pragma unroll
            for (int i = 0; i < TOPK; ++i) other[i] = __shfl_xor(top[qs][i], step, 64);
            #pragma unroll
            for (int i = 0; i < TOPK; ++i)
                if (other[i] > top[qs][TOPK - 1]) topk_insert(top[qs], other[i]);
        }
    }

    // lanes 0..15 hold the final per-query top-10 for q = qt*256 + wv*32 + qs*16 + lane
    if ((lane >> 4) == 0) {
        #pragma unroll
        for (int qs = 0; qs < 2; ++qs) {
            const int q = qt * 256 + wv * 32 + qs * 16 + lane;
            float* dst = partial + ((size_t)nc * NQ + q) * TOPK;
            #pragma unroll
            for (int i = 0; i < TOPK; ++i) dst[i] = top[qs][i];
        }
    }
}

// ---------- merge chunks, emit k-th squared distance ----------
__global__ void final_merge(const float* __restrict__ partial, float* __restrict__ out) {
    int q = blockIdx.x * 256 + threadIdx.x;
    if (q >= NQ) return;
    float top[TOPK];
    #pragma unroll
    for (int i = 0; i < TOPK; ++i) top[i] = -1e30f;
    for (int c = 0; c < NCHUNK; ++c) {
        const float* p = partial + ((size_t)c * NQ + q) * TOPK;
        #pragma unroll
        for (int i = 0; i < TOPK; ++i) {
            float x = p[i];
            if (x > top[TOPK - 1]) topk_insert(top, x);
        }
    }
    out[q] = 2.0f - 2.0f * top[TOPK - 1];
}

extern "C" void kernel_launch(void* const* d_in, const int* in_sizes, int n_in,
                              void* d_out, int out_size, void* d_ws, size_t ws_size,
                              hipStream_t stream) {
    const float* features = (const float*)d_in[0];
    const float* dbf      = (const float*)d_in[2];
    float* out = (float*)d_out;

    ushort_t* dbb = (ushort_t*)d_ws;                         // [NPAD][512] bf16   ~102.8 MB
    ushort_t* qbn = dbb + (size_t)NPAD * ND;                 // [2048][512] bf16   ~2 MB
    float* partial = (float*)(qbn + (size_t)NQ * ND);        // [NCHUNK][2048][10] ~8.0 MB

    normalize_rows<<<NPAD / 4, 256, 0, stream>>>(dbf, dbb, NDB, NPAD);
    normalize_rows<<<NQ / 4, 256, 0, stream>>>(features, qbn, NQ, NQ);
    knn_chunk<<<NWG, 512, 0, stream>>>(qbn, dbb, partial);
    final_merge<<<(NQ + 255) / 256, 256, 0, stream>>>(partial, out);
}

// Round 9
// 622.743 us; speedup vs baseline: 1.2287x; 1.2287x over previous
//
#include <hip/hip_runtime.h>
#include <hip/hip_bf16.h>

typedef unsigned short ushort_t;
typedef __attribute__((ext_vector_type(8))) short short8;
typedef __attribute__((ext_vector_type(4))) float f32x4;
typedef __attribute__((ext_vector_type(4))) unsigned int uint4v;

#define NQ      2048
#define ND      512
#define NDB     100000
#define TOPK    10
#define BQ      256
#define BN      256
#define NQT     (NQ / BQ)             // 8
#define NNT     392                   // n tiles; 392*256 = 100352 >= 100000
#define NPAD    (NNT * BN)            // 100352
#define NWG     (NQT * NNT)           // 3136 = 8 * 392
#define PERXCD  (NWG / 8)             // 392

// async global->LDS, 16B per lane, wave-uniform LDS base + lane*16
#define GL2LDS(gp, lp) __builtin_amdgcn_global_load_lds(                      \
    (const __attribute__((address_space(1))) void*)(gp),                     \
    (__attribute__((address_space(3))) void*)(lp), 16, 0, 0)

#define BAR() do { asm volatile("" ::: "memory");                            \
                   __builtin_amdgcn_s_barrier();                             \
                   asm volatile("" ::: "memory"); } while (0)

// ---------- fp32 -> bf16 (round to nearest even) ----------
static __device__ inline ushort_t f2bf(float x) {
    unsigned u = __float_as_uint(x);
    unsigned r = (u + 0x7FFFu + ((u >> 16) & 1u)) >> 16;
    return (ushort_t)r;
}

// ---------- row L2-normalize, fp32 -> bf16; zero-fill pad rows ----------
__global__ void normalize_rows(const float* __restrict__ in, ushort_t* __restrict__ out,
                               int nvalid, int ntotal) {
    int row  = blockIdx.x * 4 + (threadIdx.x >> 6);
    int lane = threadIdx.x & 63;
    if (row >= ntotal) return;
    uint4v pk;
    if (row >= nvalid) {
        pk[0] = 0u; pk[1] = 0u; pk[2] = 0u; pk[3] = 0u;
    } else {
        const float4* src = reinterpret_cast<const float4*>(in + (size_t)row * ND);
        float4 v0 = src[lane * 2];
        float4 v1 = src[lane * 2 + 1];
        float s = v0.x*v0.x + v0.y*v0.y + v0.z*v0.z + v0.w*v0.w
                + v1.x*v1.x + v1.y*v1.y + v1.z*v1.z + v1.w*v1.w;
        #pragma unroll
        for (int off = 32; off; off >>= 1) s += __shfl_xor(s, off, 64);
        float r = rsqrtf(s);
        pk[0] = (unsigned)f2bf(v0.x * r) | ((unsigned)f2bf(v0.y * r) << 16);
        pk[1] = (unsigned)f2bf(v0.z * r) | ((unsigned)f2bf(v0.w * r) << 16);
        pk[2] = (unsigned)f2bf(v1.x * r) | ((unsigned)f2bf(v1.y * r) << 16);
        pk[3] = (unsigned)f2bf(v1.z * r) | ((unsigned)f2bf(v1.w * r) << 16);
    }
    *reinterpret_cast<uint4v*>(out + (size_t)row * ND + lane * 8) = pk;
}

__device__ inline void topk_insert(float (&top)[TOPK], float x) {
    #pragma unroll
    for (int i = 0; i < TOPK; ++i) {
        float mx = fmaxf(top[i], x);
        x = fminf(top[i], x);
        top[i] = mx;
    }
}

// ---------- 256q x 256n GEMM tile + top-10, m201-style 4-phase K-steps ----------
// 512 threads, 8 waves (wm=wv>>1 q-quadrant of 64, wn=wv&1 n-half of 128).
// A,B double-buffered by K-parity in LDS (128 KB). Per K-step (BK=64): 4 phases
// {frag ds_reads | stage one half-tile | barrier | setprio+16 MFMA | barrier}.
// Counted vmcnt: A staged 2 ahead (same-parity buf, safe after ph2), B 1 ahead.
// SWAPPED mfma(B,A): acc[qf][nf][r] -> q = wm*64+qf*16+(lane&15). Selection once
// per block after the K-loop, fully in registers, then LDS merge of wn-halves.
__global__ __launch_bounds__(512, 2)
void knn_big(const ushort_t* __restrict__ qb, const ushort_t* __restrict__ dbb,
             float* __restrict__ partial) {
    const int logical = (blockIdx.x & 7) * PERXCD + (blockIdx.x >> 3);
    const int qt = logical & (NQT - 1);
    const int nt = logical >> 3;          // NQT == 8
    const int t = threadIdx.x, lane = t & 63;
    const int wv = t >> 6, wm = wv >> 1, wn = wv & 1;
    const int l15 = lane & 15, l7 = lane & 7, lhi = lane >> 4;

    __shared__ __align__(16) ushort_t As[2][BQ * 64];   // 64 KB
    __shared__ __align__(16) ushort_t Bs[2][BN * 64];   // 64 KB

    const ushort_t* agbase = qb  + (size_t)qt * BQ * ND;
    const ushort_t* bgbase = dbb + (size_t)nt * BN * ND;

    // stage one 128-row x 64-k half-tile (16 KB): thread covers 16B-chunks t, t+512.
    // linear LDS dest (gl2lds requirement) + inverse-XOR-swizzled global source.
    auto stage_half = [&](ushort_t* dst, const ushort_t* gbase, int half, int kt) {
        const int r0 = half * 128;
        #pragma unroll
        for (int i = 0; i < 2; ++i) {
            const int chunk = t + i * 512;            // 0..1023 within half-tile
            const int row = r0 + (chunk >> 3);
            const int c = (chunk & 7) ^ (row & 7);
            GL2LDS(gbase + (size_t)row * ND + kt * 64 + c * 8, dst + r0 * 64 + chunk * 8);
        }
    };
    // fragment reads (proven conflict-free pattern): chunk j XOR row&7 (==lane&7)
    auto rdA = [&](const ushort_t* buf, int qf, int ksub) {
        const int row = wm * 64 + qf * 16 + l15;
        return *reinterpret_cast<const short8*>(buf + row * 64 + (((ksub * 4 + lhi) ^ l7) * 8));
    };
    auto rdB = [&](const ushort_t* buf, int nf, int ksub) {
        const int row = wn * 128 + nf * 16 + l15;
        return *reinterpret_cast<const short8*>(buf + row * 64 + (((ksub * 4 + lhi) ^ l7) * 8));
    };

    f32x4 acc[4][8];
    #pragma unroll
    for (int a = 0; a < 4; ++a)
        #pragma unroll
        for (int b = 0; b < 8; ++b)
            acc[a][b] = (f32x4){0.f, 0.f, 0.f, 0.f};

    // prologue: K-steps 0 and 1 fully staged (16 loads/thread)
    stage_half(&As[0][0], agbase, 0, 0);
    stage_half(&As[0][0], agbase, 1, 0);
    stage_half(&Bs[0][0], bgbase, 0, 0);
    stage_half(&Bs[0][0], bgbase, 1, 0);
    stage_half(&As[1][0], agbase, 0, 1);
    stage_half(&As[1][0], agbase, 1, 1);
    stage_half(&Bs[1][0], bgbase, 0, 1);
    stage_half(&Bs[1][0], bgbase, 1, 1);

    #pragma unroll
    for (int kt = 0; kt < 8; ++kt) {
        const int c = kt & 1;
        const ushort_t* Ac = &As[c][0];
        const ushort_t* Bc = &Bs[c][0];
        ushort_t* An = &As[c][0];         // A(kt+2) target: same parity (safe after ph2)
        ushort_t* Bn = &Bs[c ^ 1][0];     // B(kt+1) target

        // counted wait (derived): kt0 leaves A1,B1 (8 loads) in flight; steady leaves
        // A(kt+1) (4 loads); only the last K-step fully drains.
        if (kt == 0)      { asm volatile("s_waitcnt vmcnt(8)" ::: "memory"); }
        else if (kt == 7) { asm volatile("s_waitcnt vmcnt(0)" ::: "memory"); }
        else              { asm volatile("s_waitcnt vmcnt(4)" ::: "memory"); }
        BAR();

        short8 af0[4], af1[4], bf[4];

        // ---- ph0: ksub0, n-frags 0-3; stage B(kt+1) half 0
        #pragma unroll
        for (int qf = 0; qf < 4; ++qf) af0[qf] = rdA(Ac, qf, 0);
        #pragma unroll
        for (int nf = 0; nf < 4; ++nf) bf[nf] = rdB(Bc, nf, 0);
        if (kt >= 1 && kt < 7) stage_half(Bn, bgbase, 0, kt + 1);
        BAR();
        __builtin_amdgcn_s_setprio(1);
        #pragma unroll
        for (int qf = 0; qf < 4; ++qf)
            #pragma unroll
            for (int nf = 0; nf < 4; ++nf)
                acc[qf][nf] = __builtin_amdgcn_mfma_f32_16x16x32_bf16(bf[nf], af0[qf], acc[qf][nf], 0, 0, 0);
        __builtin_amdgcn_s_setprio(0);
        BAR();

        // ---- ph1: ksub0, n-frags 4-7; stage B(kt+1) half 1
        #pragma unroll
        for (int nf = 0; nf < 4; ++nf) bf[nf] = rdB(Bc, 4 + nf, 0);
        if (kt >= 1 && kt < 7) stage_half(Bn, bgbase, 1, kt + 1);
        BAR();
        __builtin_amdgcn_s_setprio(1);
        #pragma unroll
        for (int qf = 0; qf < 4; ++qf)
            #pragma unroll
            for (int nf = 0; nf < 4; ++nf)
                acc[qf][4 + nf] = __builtin_amdgcn_mfma_f32_16x16x32_bf16(bf[nf], af0[qf], acc[qf][4 + nf], 0, 0, 0);
        __builtin_amdgcn_s_setprio(0);
        BAR();

        // ---- ph2: ksub1, n-frags 0-3 (last A-reads of this buffer)
        #pragma unroll
        for (int qf = 0; qf < 4; ++qf) af1[qf] = rdA(Ac, qf, 1);
        #pragma unroll
        for (int nf = 0; nf < 4; ++nf) bf[nf] = rdB(Bc, nf, 1);
        BAR();
        __builtin_amdgcn_s_setprio(1);
        #pragma unroll
        for (int qf = 0; qf < 4; ++qf)
            #pragma unroll
            for (int nf = 0; nf < 4; ++nf)
                acc[qf][nf] = __builtin_amdgcn_mfma_f32_16x16x32_bf16(bf[nf], af1[qf], acc[qf][nf], 0, 0, 0);
        __builtin_amdgcn_s_setprio(0);
        BAR();

        // ---- ph3: ksub1, n-frags 4-7; stage A(kt+2) both halves (A-reads done at ph2)
        #pragma unroll
        for (int nf = 0; nf < 4; ++nf) bf[nf] = rdB(Bc, 4 + nf, 1);
        if (kt < 6) {
            stage_half(An, agbase, 0, kt + 2);
            stage_half(An, agbase, 1, kt + 2);
        }
        BAR();
        __builtin_amdgcn_s_setprio(1);
        #pragma unroll
        for (int qf = 0; qf < 4; ++qf)
            #pragma unroll
            for (int nf = 0; nf < 4; ++nf)
                acc[qf][4 + nf] = __builtin_amdgcn_mfma_f32_16x16x32_bf16(bf[nf], af1[qf], acc[qf][4 + nf], 0, 0, 0);
        __builtin_amdgcn_s_setprio(0);
        BAR();
    }

    // ---- selection: once per block, fully unrolled (rule #20), regs only
    __syncthreads();
    float* Ms = reinterpret_cast<float*>(&As[0][0]);   // [256 q][2 wn][10] = 20 KB

    #pragma unroll
    for (int qf = 0; qf < 4; ++qf) {
        float top[TOPK];
        #pragma unroll
        for (int i = 0; i < TOPK; ++i) top[i] = -1e30f;
        #pragma unroll
        for (int nf = 0; nf < 8; ++nf) {
            float m0 = fmaxf(fmaxf(acc[qf][nf][0], acc[qf][nf][1]),
                             fmaxf(acc[qf][nf][2], acc[qf][nf][3]));
            if (m0 > top[TOPK - 1]) {
                #pragma unroll
                for (int r = 0; r < 4; ++r) {
                    float v = acc[qf][nf][r];
                    if (v > top[TOPK - 1]) topk_insert(top, v);
                }
            }
        }
        // merge 4 lanes sharing this query (lane ^ 16, lane ^ 32)
        #pragma unroll
        for (int step = 16; step <= 32; step <<= 1) {
            float other[TOPK];
            #pragma unroll
            for (int i = 0; i < TOPK; ++i) other[i] = __shfl_xor(top[i], step, 64);
            #pragma unroll
            for (int i = 0; i < TOPK; ++i)
                if (other[i] > top[TOPK - 1]) topk_insert(top, other[i]);
        }
        if (lhi == 0) {
            const int qloc = wm * 64 + qf * 16 + l15;
            #pragma unroll
            for (int i = 0; i < TOPK; ++i) Ms[(qloc * 2 + wn) * TOPK + i] = top[i];
        }
    }
    __syncthreads();
    if (t < BQ) {
        float best[TOPK];
        #pragma unroll
        for (int i = 0; i < TOPK; ++i) best[i] = -1e30f;
        #pragma unroll
        for (int s = 0; s < 2; ++s)
            #pragma unroll
            for (int i = 0; i < TOPK; ++i) {
                float x = Ms[(t * 2 + s) * TOPK + i];
                if (x > best[TOPK - 1]) topk_insert(best, x);
            }
        float* dst = partial + ((size_t)nt * NQ + qt * BQ + t) * TOPK;
        #pragma unroll
        for (int i = 0; i < TOPK; ++i) dst[i] = best[i];
    }
}

// ---------- merge 392 chunks per query: one wave per query ----------
__global__ void final_merge(const float* __restrict__ partial, float* __restrict__ out) {
    const int q = blockIdx.x * 4 + (threadIdx.x >> 6);
    const int lane = threadIdx.x & 63;
    if (q >= NQ) return;
    float top[TOPK];
    #pragma unroll
    for (int i = 0; i < TOPK; ++i) top[i] = -1e30f;
    for (int c = lane; c < NNT; c += 64) {
        const float* p = partial + ((size_t)c * NQ + q) * TOPK;
        #pragma unroll
        for (int i = 0; i < TOPK; ++i) {
            float x = p[i];
            if (x > top[TOPK - 1]) topk_insert(top, x);
        }
    }
    #pragma unroll
    for (int step = 1; step <= 32; step <<= 1) {
        float other[TOPK];
        #pragma unroll
        for (int i = 0; i < TOPK; ++i) other[i] = __shfl_xor(top[i], step, 64);
        #pragma unroll
        for (int i = 0; i < TOPK; ++i)
            if (other[i] > top[TOPK - 1]) topk_insert(top, other[i]);
    }
    if (lane == 0) out[q] = 2.0f - 2.0f * top[TOPK - 1];
}

extern "C" void kernel_launch(void* const* d_in, const int* in_sizes, int n_in,
                              void* d_out, int out_size, void* d_ws, size_t ws_size,
                              hipStream_t stream) {
    const float* features = (const float*)d_in[0];
    const float* dbf      = (const float*)d_in[2];
    float* out = (float*)d_out;

    ushort_t* dbb = (ushort_t*)d_ws;                         // [NPAD][512] bf16   ~102.8 MB
    ushort_t* qbn = dbb + (size_t)NPAD * ND;                 // [2048][512] bf16   ~2 MB
    float* partial = (float*)(qbn + (size_t)NQ * ND);        // [NNT][2048][10]    ~32.1 MB

    normalize_rows<<<NPAD / 4, 256, 0, stream>>>(dbf, dbb, NDB, NPAD);
    normalize_rows<<<NQ / 4, 256, 0, stream>>>(features, qbn, NQ, NQ);
    knn_big<<<NWG, 512, 0, stream>>>(qbn, dbb, partial);
    final_merge<<<NQ / 4, 256, 0, stream>>>(partial, out);
}